// Round 1
// baseline (377.574 us; speedup 1.0000x reference)
//
#include <hip/hip_runtime.h>

#define KK 32
#define BATCH 512
#define DD 2048
#define NODEF (BATCH * KK)  // floats per node slab, layout [node][batch][k]

// ---------------------------------------------------------------------------
// Per-lane full-K node: p[32] (registers) -> log_matmul_exp result, in place.
// W access is wave-uniform -> scalar loads (SMEM pipe), FMA src0 from SGPR.
// No LDS, no barriers, no cross-lane ops.
// ---------------------------------------------------------------------------
__device__ __forceinline__ void node32(float p[KK], const float* __restrict__ Wn) {
  // per-lane max over 32 regs (pairwise tree; max is order-exact)
  float t[16];
#pragma unroll
  for (int i = 0; i < 16; ++i) t[i] = fmaxf(p[2 * i], p[2 * i + 1]);
#pragma unroll
  for (int s = 8; s >= 1; s >>= 1)
#pragma unroll
    for (int i = 0; i < s; ++i) t[i] = fmaxf(t[i], t[i + s]);
  const float m = t[0];

  // exp in place
#pragma unroll
  for (int i = 0; i < KK; ++i) p[i] = __expf(p[i] - m);

  float acc[KK];
#pragma unroll
  for (int j = 0; j < KK; ++j) acc[j] = 0.0f;

  // i-outer: 32 independent accumulator chains (full ILP).
  // unroll 8 -> ~2 KB code per node, S-loads batched 8 rows at a time.
#pragma unroll 8
  for (int i = 0; i < KK; ++i) {
    const float ei = p[i];
#pragma unroll
    for (int j = 0; j < KK; ++j)
      acc[j] = fmaf(ei, Wn[i * KK + j], acc[j]);
  }

#pragma unroll
  for (int j = 0; j < KK; ++j) p[j] = __logf(acc[j]) + m;
}

// ---------------------------------------------------------------------------
// load two K-vectors (float4 x8 each) and sum into p[32]
// ---------------------------------------------------------------------------
__device__ __forceinline__ void pairsum_g(const float* __restrict__ a,
                                          const float* __restrict__ b,
                                          float p[KK]) {
  const float4* u = reinterpret_cast<const float4*>(a);
  const float4* v = reinterpret_cast<const float4*>(b);
  float4 ub[8], vb[8];
#pragma unroll
  for (int q = 0; q < 8; ++q) ub[q] = u[q];
#pragma unroll
  for (int q = 0; q < 8; ++q) vb[q] = v[q];
#pragma unroll
  for (int q = 0; q < 8; ++q) {
    p[4 * q + 0] = ub[q].x + vb[q].x;
    p[4 * q + 1] = ub[q].y + vb[q].y;
    p[4 * q + 2] = ub[q].z + vb[q].z;
    p[4 * q + 3] = ub[q].w + vb[q].w;
  }
}

__device__ __forceinline__ void store32(float* __restrict__ dst, const float p[KK]) {
  float4* d = reinterpret_cast<float4*>(dst);
#pragma unroll
  for (int q = 0; q < 8; ++q)
    d[q] = make_float4(p[4 * q], p[4 * q + 1], p[4 * q + 2], p[4 * q + 3]);
}

// ---------------------------------------------------------------------------
// kern1: levels 1-3 (8 leaves -> 1 node). grid (256 chunks, 2), 256 thr.
// Each wave owns 64 batches; each lane owns one batch's full K vector.
// Zero barriers, zero LDS.
// ---------------------------------------------------------------------------
__global__ __launch_bounds__(256) void kern1(const float* __restrict__ x,
                                             const float* __restrict__ W,
                                             float* __restrict__ o) {
  const int tid = threadIdx.x;
  const int lane = tid & 63;
  const int wid = tid >> 6;
  const int chunk = blockIdx.x;  // 0..255
  const int b = blockIdx.y * 256 + wid * 64 + lane;

  const float* xb = x + (size_t)b * (DD * KK) + (size_t)chunk * 8 * KK;
  const float* WL1 = W + (size_t)(4 * chunk) * (KK * KK);
  const float* WL2 = W + (size_t)(1024 + 2 * chunk) * (KK * KK);
  const float* WL3 = W + (size_t)(1536 + chunk) * (KK * KK);

  float s01[KK], s23[KK], p[KK];

  // L1 nodes 4c..4c+3, fused pairwise into L2 inputs
  pairsum_g(xb + 0 * KK, xb + 1 * KK, s01);
  node32(s01, WL1 + 0 * 1024);
  pairsum_g(xb + 2 * KK, xb + 3 * KK, p);
  node32(p, WL1 + 1 * 1024);
#pragma unroll
  for (int j = 0; j < KK; ++j) s01[j] += p[j];

  pairsum_g(xb + 4 * KK, xb + 5 * KK, s23);
  node32(s23, WL1 + 2 * 1024);
  pairsum_g(xb + 6 * KK, xb + 7 * KK, p);
  node32(p, WL1 + 3 * 1024);
#pragma unroll
  for (int j = 0; j < KK; ++j) s23[j] += p[j];

  // L2 nodes 2c, 2c+1
  node32(s01, WL2 + 0 * 1024);
  node32(s23, WL2 + 1 * 1024);
#pragma unroll
  for (int j = 0; j < KK; ++j) s01[j] += s23[j];

  // L3 node c
  node32(s01, WL3);

  store32(o + ((size_t)chunk * BATCH + b) * KK, s01);
}

// ---------------------------------------------------------------------------
// kernT: two tree levels (4 child nodes -> 1). grid (F_hi, 2), 256 thr.
// ---------------------------------------------------------------------------
__global__ __launch_bounds__(256) void kernT(const float* __restrict__ in,
                                             const float* __restrict__ W,
                                             float* __restrict__ o, int lo,
                                             int hi) {
  const int tid = threadIdx.x;
  const int lane = tid & 63;
  const int wid = tid >> 6;
  const int n = blockIdx.x;
  const int b = blockIdx.y * 256 + wid * 64 + lane;

  const float* i0 = in + ((size_t)(4 * n) * BATCH + b) * KK;

  float s01[KK], p[KK];

  pairsum_g(i0, i0 + NODEF, s01);
  node32(s01, W + (size_t)(lo + 2 * n + 0) * (KK * KK));
  pairsum_g(i0 + 2 * (size_t)NODEF, i0 + 3 * (size_t)NODEF, p);
  node32(p, W + (size_t)(lo + 2 * n + 1) * (KK * KK));
#pragma unroll
  for (int j = 0; j < KK; ++j) s01[j] += p[j];

  node32(s01, W + (size_t)(hi + n) * (KK * KK));

  store32(o + ((size_t)n * BATCH + b) * KK, s01);
}

// ---------------------------------------------------------------------------
// kernF: levels 10-11 + mixture logsumexp. grid (1, 2), 256 thr.
// Final LSE over K is per-lane (lane owns the full vector) -> no cross-lane.
// ---------------------------------------------------------------------------
__global__ __launch_bounds__(256) void kernF(const float* __restrict__ in,
                                             const float* __restrict__ W,
                                             const float* __restrict__ mixw,
                                             float* __restrict__ out) {
  const int tid = threadIdx.x;
  const int lane = tid & 63;
  const int wid = tid >> 6;
  const int b = blockIdx.y * 256 + wid * 64 + lane;

  const float* i0 = in + (size_t)b * KK;

  float s01[KK], p[KK];

  pairsum_g(i0, i0 + NODEF, s01);
  node32(s01, W + (size_t)2044 * (KK * KK));
  pairsum_g(i0 + 2 * (size_t)NODEF, i0 + 3 * (size_t)NODEF, p);
  node32(p, W + (size_t)2045 * (KK * KK));
#pragma unroll
  for (int j = 0; j < KK; ++j) s01[j] += p[j];

  node32(s01, W + (size_t)2046 * (KK * KK));

  // log_softmax(mix_logw): wave-uniform -> scalar loads, computed per lane
  float wv[KK];
#pragma unroll
  for (int i = 0; i < KK; ++i) wv[i] = mixw[i];
  float t[16];
#pragma unroll
  for (int i = 0; i < 16; ++i) t[i] = fmaxf(wv[2 * i], wv[2 * i + 1]);
#pragma unroll
  for (int s = 8; s >= 1; s >>= 1)
#pragma unroll
    for (int i = 0; i < s; ++i) t[i] = fmaxf(t[i], t[i + s]);
  const float wm = t[0];
  float ws = 0.0f;
#pragma unroll
  for (int i = 0; i < KK; ++i) ws += __expf(wv[i] - wm);
  const float lsew = __logf(ws) + wm;

  // flat = 2*root + logw ; per-lane logsumexp over K
  float f[KK];
#pragma unroll
  for (int j = 0; j < KK; ++j) f[j] = 2.0f * s01[j] + (wv[j] - lsew);
#pragma unroll
  for (int i = 0; i < 16; ++i) t[i] = fmaxf(f[2 * i], f[2 * i + 1]);
#pragma unroll
  for (int s = 8; s >= 1; s >>= 1)
#pragma unroll
    for (int i = 0; i < s; ++i) t[i] = fmaxf(t[i], t[i + s]);
  const float m2 = t[0];
  float ss = 0.0f;
#pragma unroll
  for (int j = 0; j < KK; ++j) ss += __expf(f[j] - m2);
  out[b] = __logf(ss) + m2;
}

// ---------------------------------------------------------------------------
extern "C" void kernel_launch(void* const* d_in, const int* in_sizes, int n_in,
                              void* d_out, int out_size, void* d_ws,
                              size_t ws_size, hipStream_t stream) {
  const float* x = (const float*)d_in[0];     // [512][2048][32]
  const float* W = (const float*)d_in[1];     // [2047][32][32]
  // d_in[2] = fold_idx: always (2f, 2f+1) pairs per level -> hardcoded
  const float* mixw = (const float*)d_in[3];  // [32]
  float* out = (float*)d_out;                 // [512]

  float* A = (float*)d_ws;               // 256 node slabs, [node][batch][k]
  float* Bb = A + (size_t)256 * NODEF;   // 64 node slabs

  kern1<<<dim3(256, 2), 256, 0, stream>>>(x, W, A);              // L1-3  -> A[256]
  kernT<<<dim3(64, 2), 256, 0, stream>>>(A, W, Bb, 1792, 1920);  // L4-5  -> B[64]
  kernT<<<dim3(16, 2), 256, 0, stream>>>(Bb, W, A, 1984, 2016);  // L6-7  -> A[16]
  kernT<<<dim3(4, 2), 256, 0, stream>>>(A, W, Bb, 2032, 2040);   // L8-9  -> B[4]
  kernF<<<dim3(1, 2), 256, 0, stream>>>(Bb, W, mixw, out);       // L10-11 + LSE
}